// Round 4
// baseline (167.026 us; speedup 1.0000x reference)
//
#include <hip/hip_runtime.h>

// Problem constants (fixed by the reference)
#define NN 512
#define KK 17
#define WW 48
#define HH 64
#define HW (WW * HH)          // 3072 pixels per (n,k)
#define NK (NN * KK)          // 8704 items
// One block per n: 512 blocks == exactly 2 blocks/CU on 256 CUs, one generation.

// Loss = mean over [N,K,H,W] of (tw*mask * (g - teacher))^2, g separable:
// g = ex[w]*ey[h]. Stage ex (float4) + ey for all 17 joints of one sample in
// LDS, then stream the 51 KB teacher slab with a 2-deep register pipeline
// (prefetch item i+1 while computing item i). One partial per block -> ws.

__global__ __launch_bounds__(256) void reg2hm_partial_kernel(
    const float* __restrict__ pred,      // [N,K,2]
    const float* __restrict__ sigma,     // [N,K,2]
    const float* __restrict__ teacher,   // [N,K,H,W]
    const float* __restrict__ twgt,      // [N,K,1]
    float* __restrict__ ws)              // [NN] partial sums
{
    __shared__ float4 ex4[KK][WW / 4];   // 17 x 12 float4
    __shared__ float  eys[KK][HH];       // 17 x 64
    __shared__ float  sw[KK];
    __shared__ float  wave_sums[4];

    const int n   = blockIdx.x;
    const int nk0 = n * KK;
    const int t   = threadIdx.x;

    // Per-item weight (mask * target_weight)
    if (t < KK) {
        const int nk = nk0 + t;
        const float mu_x = pred[nk * 2 + 0] * (float)WW;
        const float mu_y = pred[nk * 2 + 1] * (float)HH;
        const float sx   = sigma[nk * 2 + 0];
        const float sy   = sigma[nk * 2 + 1];
        const bool m = (mu_x - 3.0f * sx < (float)WW) &&
                       (mu_y - 3.0f * sy < (float)HH) &&
                       (mu_x + 3.0f * sx + 1.0f >= 0.0f) &&
                       (mu_y + 3.0f * sy + 1.0f >= 0.0f);
        sw[t] = twgt[nk] * (m ? 1.0f : 0.0f);
    }

    // Stage separable exponentials: 17*(48+64) = 1904 entries.
    float* exf = (float*)ex4;
    for (int i = t; i < KK * (WW + HH); i += 256) {
        const int item = i / (WW + HH);
        const int r    = i - item * (WW + HH);
        const int nk   = nk0 + item;
        if (r < WW) {
            const float mu = pred[nk * 2 + 0] * (float)WW;
            const float s  = sigma[nk * 2 + 0];
            const float d  = (float)r - mu;
            exf[item * WW + r] = __expf(-d * d * (0.5f / (s * s + 1e-9f)));
        } else {
            const float mu = pred[nk * 2 + 1] * (float)HH;
            const float s  = sigma[nk * 2 + 1];
            const float d  = (float)(r - WW) - mu;
            eys[item][r - WW] = __expf(-d * d * (0.5f / (s * s + 1e-9f)));
        }
    }
    __syncthreads();

    // Item-invariant index math: float4 index i in [0,768), h = i/12, s = i%12.
    const int i0 = t;
    const int i1 = t + 256;
    const int i2 = t + 512;
    const int h0 = i0 / 12, s0 = i0 - h0 * 12;
    const int h1 = i1 / 12, s1 = i1 - h1 * 12;
    const int h2 = i2 / 12, s2 = i2 - h2 * 12;

    const float4* tp = (const float4*)(teacher + (size_t)nk0 * HW);

    // 2-deep software pipeline over the 17 items (768 float4 each).
    float4 c0 = tp[i0], c1 = tp[i1], c2 = tp[i2];
    float total = 0.0f;
#pragma unroll 1
    for (int item = 0; item < KK; ++item) {
        float4 n0, n1, n2;
        if (item < KK - 1) {
            const float4* np_ = tp + (item + 1) * (HW / 4);
            n0 = np_[i0]; n1 = np_[i1]; n2 = np_[i2];
        }
        const float4 e0 = ex4[item][s0];
        const float4 e1 = ex4[item][s1];
        const float4 e2 = ex4[item][s2];
        const float  y0 = eys[item][h0];
        const float  y1 = eys[item][h1];
        const float  y2 = eys[item][h2];

        float acc = 0.0f;
        {
            const float d0 = e0.x * y0 - c0.x, d1 = e0.y * y0 - c0.y;
            const float d2 = e0.z * y0 - c0.z, d3 = e0.w * y0 - c0.w;
            acc += d0 * d0 + d1 * d1 + d2 * d2 + d3 * d3;
        }
        {
            const float d0 = e1.x * y1 - c1.x, d1 = e1.y * y1 - c1.y;
            const float d2 = e1.z * y1 - c1.z, d3 = e1.w * y1 - c1.w;
            acc += d0 * d0 + d1 * d1 + d2 * d2 + d3 * d3;
        }
        {
            const float d0 = e2.x * y2 - c2.x, d1 = e2.y * y2 - c2.y;
            const float d2 = e2.z * y2 - c2.z, d3 = e2.w * y2 - c2.w;
            acc += d0 * d0 + d1 * d1 + d2 * d2 + d3 * d3;
        }
        total += sw[item] * sw[item] * acc;
        c0 = n0; c1 = n1; c2 = n2;
    }

    // Wave(64) shuffle reduction, then cross-wave via LDS.
#pragma unroll
    for (int off = 32; off > 0; off >>= 1)
        total += __shfl_down(total, off, 64);

    const int wave = t >> 6;
    const int lane = t & 63;
    if (lane == 0) wave_sums[wave] = total;
    __syncthreads();

    if (t == 0)
        ws[n] = wave_sums[0] + wave_sums[1] + wave_sums[2] + wave_sums[3];
}

__global__ __launch_bounds__(256) void reg2hm_final_kernel(
    const float* __restrict__ ws, float* __restrict__ out)
{
    __shared__ float wave_sums[4];
    const int t = threadIdx.x;
    float sum = 0.0f;
    for (int i = t; i < NN; i += 256) sum += ws[i];
#pragma unroll
    for (int off = 32; off > 0; off >>= 1)
        sum += __shfl_down(sum, off, 64);
    const int wave = t >> 6;
    const int lane = t & 63;
    if (lane == 0) wave_sums[wave] = sum;
    __syncthreads();
    if (t == 0) {
        const float total = wave_sums[0] + wave_sums[1] + wave_sums[2] + wave_sums[3];
        out[0] = total * (1.0f / ((float)NN * KK * HW));
    }
}

extern "C" void kernel_launch(void* const* d_in, const int* in_sizes, int n_in,
                              void* d_out, int out_size, void* d_ws, size_t ws_size,
                              hipStream_t stream) {
    const float* pred    = (const float*)d_in[0];
    const float* sigma   = (const float*)d_in[1];
    const float* teacher = (const float*)d_in[2];
    const float* twgt    = (const float*)d_in[3];
    float* out = (float*)d_out;
    float* ws  = (float*)d_ws;   // needs NN*4 = 2048 bytes

    reg2hm_partial_kernel<<<NN, 256, 0, stream>>>(pred, sigma, teacher, twgt, ws);
    reg2hm_final_kernel<<<1, 256, 0, stream>>>(ws, out);
}

// Round 6
// 154.800 us; speedup vs baseline: 1.0790x; 1.0790x over previous
//
#include <hip/hip_runtime.h>

// Problem constants (fixed by the reference)
#define NN 512
#define KK 17
#define WW 48
#define HH 64
#define HW (WW * HH)          // 3072 pixels per (n,k)
#define NK (NN * KK)          // 8704 items
// One block per n: 512 blocks == exactly 2 blocks/CU on 256 CUs, one generation.

// Native clang vector type — required by __builtin_nontemporal_load
// (HIP's float4 is a class and is rejected).
typedef float fv4 __attribute__((ext_vector_type(4)));

// Loss = mean over [N,K,H,W] of (tw*mask * (g - teacher))^2, g separable:
// g = ex[w]*ey[h]. Stage ex (fv4) + ey for all 17 joints of one sample in
// LDS, then stream the 51 KB teacher slab with a 2-deep register pipeline.
// Teacher reads use NONTEMPORAL loads: the harness leaves L3 full of dirty
// 0xAA poison lines (428 MB d_ws fill) every timed iteration; regular reads
// evict them -> ~107 MB of victim writebacks contend with our reads. nt
// streaming loads skip the allocation, halving HBM traffic during the kernel.

__global__ __launch_bounds__(256) void reg2hm_partial_kernel(
    const float* __restrict__ pred,      // [N,K,2]
    const float* __restrict__ sigma,     // [N,K,2]
    const float* __restrict__ teacher,   // [N,K,H,W]
    const float* __restrict__ twgt,      // [N,K,1]
    float* __restrict__ ws)              // [NN] partial sums
{
    __shared__ fv4   ex4[KK][WW / 4];    // 17 x 12 fv4
    __shared__ float eys[KK][HH];        // 17 x 64
    __shared__ float sw[KK];
    __shared__ float wave_sums[4];

    const int n   = blockIdx.x;
    const int nk0 = n * KK;
    const int t   = threadIdx.x;

    // Per-item weight (mask * target_weight)
    if (t < KK) {
        const int nk = nk0 + t;
        const float mu_x = pred[nk * 2 + 0] * (float)WW;
        const float mu_y = pred[nk * 2 + 1] * (float)HH;
        const float sx   = sigma[nk * 2 + 0];
        const float sy   = sigma[nk * 2 + 1];
        const bool m = (mu_x - 3.0f * sx < (float)WW) &&
                       (mu_y - 3.0f * sy < (float)HH) &&
                       (mu_x + 3.0f * sx + 1.0f >= 0.0f) &&
                       (mu_y + 3.0f * sy + 1.0f >= 0.0f);
        sw[t] = twgt[nk] * (m ? 1.0f : 0.0f);
    }

    // Stage separable exponentials: 17*(48+64) = 1904 entries.
    float* exf = (float*)ex4;
    for (int i = t; i < KK * (WW + HH); i += 256) {
        const int item = i / (WW + HH);
        const int r    = i - item * (WW + HH);
        const int nk   = nk0 + item;
        if (r < WW) {
            const float mu = pred[nk * 2 + 0] * (float)WW;
            const float s  = sigma[nk * 2 + 0];
            const float d  = (float)r - mu;
            exf[item * WW + r] = __expf(-d * d * (0.5f / (s * s + 1e-9f)));
        } else {
            const float mu = pred[nk * 2 + 1] * (float)HH;
            const float s  = sigma[nk * 2 + 1];
            const float d  = (float)(r - WW) - mu;
            eys[item][r - WW] = __expf(-d * d * (0.5f / (s * s + 1e-9f)));
        }
    }
    __syncthreads();

    // Item-invariant index math: fv4 index i in [0,768), h = i/12, s = i%12.
    const int i0 = t;
    const int i1 = t + 256;
    const int i2 = t + 512;
    const int h0 = i0 / 12, s0 = i0 - h0 * 12;
    const int h1 = i1 / 12, s1 = i1 - h1 * 12;
    const int h2 = i2 / 12, s2 = i2 - h2 * 12;

    const fv4* tp = (const fv4*)(teacher + (size_t)nk0 * HW);

    // 2-deep software pipeline over the 17 items (768 fv4 each),
    // all teacher reads nontemporal (streaming, no cache allocation).
    fv4 c0 = __builtin_nontemporal_load(tp + i0);
    fv4 c1 = __builtin_nontemporal_load(tp + i1);
    fv4 c2 = __builtin_nontemporal_load(tp + i2);
    float total = 0.0f;
#pragma unroll 1
    for (int item = 0; item < KK; ++item) {
        fv4 n0, n1, n2;
        if (item < KK - 1) {
            const fv4* np_ = tp + (item + 1) * (HW / 4);
            n0 = __builtin_nontemporal_load(np_ + i0);
            n1 = __builtin_nontemporal_load(np_ + i1);
            n2 = __builtin_nontemporal_load(np_ + i2);
        }
        const fv4   e0 = ex4[item][s0];
        const fv4   e1 = ex4[item][s1];
        const fv4   e2 = ex4[item][s2];
        const float y0 = eys[item][h0];
        const float y1 = eys[item][h1];
        const float y2 = eys[item][h2];

        float acc = 0.0f;
        {
            const fv4 d = e0 * y0 - c0;
            acc += d.x * d.x + d.y * d.y + d.z * d.z + d.w * d.w;
        }
        {
            const fv4 d = e1 * y1 - c1;
            acc += d.x * d.x + d.y * d.y + d.z * d.z + d.w * d.w;
        }
        {
            const fv4 d = e2 * y2 - c2;
            acc += d.x * d.x + d.y * d.y + d.z * d.z + d.w * d.w;
        }
        total += sw[item] * sw[item] * acc;
        c0 = n0; c1 = n1; c2 = n2;
    }

    // Wave(64) shuffle reduction, then cross-wave via LDS.
#pragma unroll
    for (int off = 32; off > 0; off >>= 1)
        total += __shfl_down(total, off, 64);

    const int wave = t >> 6;
    const int lane = t & 63;
    if (lane == 0) wave_sums[wave] = total;
    __syncthreads();

    if (t == 0)
        ws[n] = wave_sums[0] + wave_sums[1] + wave_sums[2] + wave_sums[3];
}

__global__ __launch_bounds__(256) void reg2hm_final_kernel(
    const float* __restrict__ ws, float* __restrict__ out)
{
    __shared__ float wave_sums[4];
    const int t = threadIdx.x;
    float sum = 0.0f;
    for (int i = t; i < NN; i += 256) sum += ws[i];
#pragma unroll
    for (int off = 32; off > 0; off >>= 1)
        sum += __shfl_down(sum, off, 64);
    const int wave = t >> 6;
    const int lane = t & 63;
    if (lane == 0) wave_sums[wave] = sum;
    __syncthreads();
    if (t == 0) {
        const float total = wave_sums[0] + wave_sums[1] + wave_sums[2] + wave_sums[3];
        out[0] = total * (1.0f / ((float)NN * KK * HW));
    }
}

extern "C" void kernel_launch(void* const* d_in, const int* in_sizes, int n_in,
                              void* d_out, int out_size, void* d_ws, size_t ws_size,
                              hipStream_t stream) {
    const float* pred    = (const float*)d_in[0];
    const float* sigma   = (const float*)d_in[1];
    const float* teacher = (const float*)d_in[2];
    const float* twgt    = (const float*)d_in[3];
    float* out = (float*)d_out;
    float* ws  = (float*)d_ws;   // needs NN*4 = 2048 bytes

    reg2hm_partial_kernel<<<NN, 256, 0, stream>>>(pred, sigma, teacher, twgt, ws);
    reg2hm_final_kernel<<<1, 256, 0, stream>>>(ws, out);
}